// Round 2
// baseline (4401.749 us; speedup 1.0000x reference)
//
#include <hip/hip_runtime.h>
#include <hip/hip_bf16.h>

// Problem constants (fixed by the reference)
#define S     2048
#define HID   4096
#define NH    32
#define NKV   8
#define DH    128
#define KVD   1024   // NKV*DH
#define QT    8      // queries per attention block
#define MAXK  1040   // >= n_init + (QT-1) + n_local = 4+7+1024 = 1035

typedef unsigned short ushort_t;
typedef __attribute__((ext_vector_type(8))) __bf16 bf16x8;
typedef __attribute__((ext_vector_type(8))) unsigned short u16x8;
typedef __attribute__((ext_vector_type(4))) float f32x4;

static __device__ __forceinline__ unsigned short f2b(float f) {
    union { float f; unsigned int i; } x; x.f = f;
    unsigned int r = (x.i + 0x7fffu + ((x.i >> 16) & 1u)) >> 16;
    return (unsigned short)r;
}
static __device__ __forceinline__ float b2f(unsigned short u) {
    union { unsigned int i; float f; } x; x.i = ((unsigned int)u) << 16; return x.f;
}

// fp32 -> bf16 conversion, 4 elems/thread, n must be divisible by 4.
__global__ __launch_bounds__(256)
void cvt_f2b(const float* __restrict__ src, ushort_t* __restrict__ dst, int n4) {
    int i = blockIdx.x * 256 + threadIdx.x;
    if (i < n4) {
        float4 v = ((const float4*)src)[i];
        ushort4 o;
        o.x = f2b(v.x); o.y = f2b(v.y); o.z = f2b(v.z); o.w = f2b(v.w);
        ((ushort4*)dst)[i] = o;
    }
}

// C[M,N] = A[M,K] @ B[N,K]^T. bf16 inputs, fp32 accum.
// F32OUT: write float C; else bf16 C.
// 64x64 block tile, BK=32, 256 threads = 4 waves; wave w owns rows [w*16, w*16+16).
// Fragment maps per verified m89/m91: A[m=lane&15][k=(lane>>4)*8+j],
// B-frag symmetric (B^T input), C/D: col=lane&15, row=(lane>>4)*4+reg.
template <bool F32OUT>
__global__ __launch_bounds__(256)
void gemm_bt(const ushort_t* __restrict__ A, const ushort_t* __restrict__ B,
             void* __restrict__ Cv, int M, int N, int K) {
    // LDS stride 40 shorts (80 B): 16B-aligned rows, 2-way bank alias (free per m136).
    __shared__ ushort_t As[64][40];
    __shared__ ushort_t Bs[64][40];

    const int tid   = threadIdx.x;
    const int w     = tid >> 6;
    const int lane  = tid & 63;
    const int mlane = lane & 15;
    const int q     = lane >> 4;
    const int m0    = blockIdx.y * 64;
    const int n0    = blockIdx.x * 64;
    const int lrow  = tid >> 2;        // 0..63
    const int lcol  = (tid & 3) * 8;   // 0,8,16,24

    f32x4 acc[4];
#pragma unroll
    for (int i = 0; i < 4; i++) acc[i] = (f32x4)(0.0f);

    const ushort_t* aptr = A + (long)(m0 + lrow) * K + lcol;
    const ushort_t* bptr = B + (long)(n0 + lrow) * K + lcol;

    for (int k0 = 0; k0 < K; k0 += 32) {
        u16x8 av = *(const u16x8*)(aptr + k0);
        u16x8 bv = *(const u16x8*)(bptr + k0);
        __syncthreads();  // previous iter's LDS reads done
        *(u16x8*)&As[lrow][lcol] = av;
        *(u16x8*)&Bs[lrow][lcol] = bv;
        __syncthreads();
        bf16x8 af = *(const bf16x8*)&As[w * 16 + mlane][q * 8];
#pragma unroll
        for (int nt = 0; nt < 4; nt++) {
            bf16x8 bfr = *(const bf16x8*)&Bs[nt * 16 + mlane][q * 8];
            acc[nt] = __builtin_amdgcn_mfma_f32_16x16x32_bf16(af, bfr, acc[nt], 0, 0, 0);
        }
    }

#pragma unroll
    for (int nt = 0; nt < 4; nt++) {
#pragma unroll
        for (int r = 0; r < 4; r++) {
            int row = m0 + w * 16 + q * 4 + r;
            int col = n0 + nt * 16 + mlane;
            if (F32OUT) ((float*)Cv)[(long)row * N + col] = acc[nt][r];
            else        ((ushort_t*)Cv)[(long)row * N + col] = f2b(acc[nt][r]);
        }
    }
}

// StreamingLLM attention: one block per (head, 8-query tile).
// Q/K/V fp32; output bf16 (feeds the bf16-MFMA O-projection).
// Phase 1: masked scores into LDS; softmax per row via 32-lane groups;
// Phase 2: P.V accumulate in fp32, write bf16.
__global__ __launch_bounds__(256)
void attn_stream(const float* __restrict__ Q, const float* __restrict__ Kb,
                 const float* __restrict__ Vb, ushort_t* __restrict__ O,
                 const int* __restrict__ n_init_p, const int* __restrict__ n_local_p) {
    __shared__ float Qs[QT][DH];
    __shared__ float scores[QT][MAXK];
    __shared__ float row_l[QT];

    const int n_init  = *n_init_p;
    const int n_local = *n_local_p;
    const int tid   = threadIdx.x;
    const int qtile = blockIdx.x & 255;   // S/QT = 256 tiles per head
    const int h     = blockIdx.x >> 8;
    const int kh    = h >> 2;             // n_rep = 4
    const int i0    = qtile * QT;
    const int iMax  = i0 + QT - 1;

    // Key list: sink [0,n_init) plus window [wstart, iMax]; merged if overlapping.
    int wstart = i0 - n_local + 1; if (wstart < 0) wstart = 0;
    int sinkN, nkeys;
    if (wstart <= n_init) { sinkN = iMax + 1; nkeys = iMax + 1; wstart = 0; }
    else                  { sinkN = n_init;  nkeys = n_init + (iMax - wstart + 1); }

    const int qi  = tid >> 5;        // 0..7
    const int l32 = tid & 31;

    // Load Q tile -> LDS
    {
        int d0 = l32 * 4;
        const float4 qv = *(const float4*)(Q + (long)(i0 + qi) * HID + h * DH + d0);
        *(float4*)&Qs[qi][d0] = qv;
    }
    __syncthreads();

    const float scale = 0.08838834764831845f; // 1/sqrt(128)
    const int i = i0 + qi;

    // Phase 1: scores
    for (int t = l32; t < nkeys; t += 32) {
        int j = (t < sinkN) ? t : (wstart + (t - sinkN));
        bool ok = (j <= i) && ((j < n_init) || (i - j < n_local));
        float s = -1e30f;
        if (ok) {
            const float* kp = Kb + (long)j * KVD + kh * DH;
            float acc = 0.0f;
#pragma unroll
            for (int dc = 0; dc < DH; dc += 4) {
                float4 kv = *(const float4*)(kp + dc);
                acc += Qs[qi][dc + 0] * kv.x + Qs[qi][dc + 1] * kv.y
                     + Qs[qi][dc + 2] * kv.z + Qs[qi][dc + 3] * kv.w;
            }
            s = acc * scale;
        }
        scores[qi][t] = s;
    }

    // Softmax per row (each 32-lane group owns one row; reads only its own writes)
    float m = -1e30f;
    for (int t = l32; t < nkeys; t += 32) m = fmaxf(m, scores[qi][t]);
#pragma unroll
    for (int o = 16; o > 0; o >>= 1) m = fmaxf(m, __shfl_xor(m, o, 32));
    float lsum = 0.0f;
    for (int t = l32; t < nkeys; t += 32) {
        float e = __expf(scores[qi][t] - m);
        scores[qi][t] = e;
        lsum += e;
    }
#pragma unroll
    for (int o = 16; o > 0; o >>= 1) lsum += __shfl_xor(lsum, o, 32);
    if (l32 == 0) row_l[qi] = lsum;
    __syncthreads();

    // Phase 2: O = (P/l) @ V ; thread owns (qi, 4 dims)
    {
        int d0 = l32 * 4;
        float a0 = 0.f, a1 = 0.f, a2 = 0.f, a3 = 0.f;
        const float* vbase = Vb + kh * DH + d0;
        for (int t = 0; t < nkeys; t++) {
            float p = scores[qi][t];
            int j = (t < sinkN) ? t : (wstart + (t - sinkN));
            float4 vv = *(const float4*)(vbase + (long)j * KVD);
            a0 += p * vv.x; a1 += p * vv.y; a2 += p * vv.z; a3 += p * vv.w;
        }
        float rl = 1.0f / row_l[qi];
        ushort_t* op = O + (long)(i0 + qi) * HID + h * DH + d0;
        op[0] = f2b(a0 * rl); op[1] = f2b(a1 * rl);
        op[2] = f2b(a2 * rl); op[3] = f2b(a3 * rl);
    }
}

extern "C" void kernel_launch(void* const* d_in, const int* in_sizes, int n_in,
                              void* d_out, int out_size, void* d_ws, size_t ws_size,
                              hipStream_t stream) {
    const float* H  = (const float*)d_in[0];  // [S, HID] fp32
    const float* Wq = (const float*)d_in[1];  // [HID, HID]
    const float* Wk = (const float*)d_in[2];  // [KVD, HID]
    const float* Wv = (const float*)d_in[3];  // [KVD, HID]
    const float* Wo = (const float*)d_in[4];  // [HID, HID]
    const int* n_init_p  = (const int*)d_in[5];
    const int* n_local_p = (const int*)d_in[6];

    // Workspace layout (bytes):
    //   Hb   bf16 [S,HID]    16.78 MB   (aliased by Ab after V-proj GEMM)
    //   Wbuf bf16 [HID,HID]  33.55 MB   (reused for Wq/Wk/Wv/Wo sequentially)
    //   Qf   fp32 [S,HID]    33.55 MB
    //   Kf   fp32 [S,KVD]     8.39 MB
    //   Vf   fp32 [S,KVD]     8.39 MB   -> total ~100.7 MB
    char* p = (char*)d_ws;
    ushort_t* Hb   = (ushort_t*)p;                 p += (size_t)S * HID * 2;
    ushort_t* Wbuf = (ushort_t*)p;                 p += (size_t)HID * HID * 2;
    float*    Qf   = (float*)p;                    p += (size_t)S * HID * 4;
    float*    Kf   = (float*)p;                    p += (size_t)S * KVD * 4;
    float*    Vf   = (float*)p;
    ushort_t* Ab   = Hb;  // Hb dead after V-proj GEMM; same size.

    dim3 blk(256);
    const int nH  = S * HID / 4, nWq = HID * HID / 4, nWk = KVD * HID / 4;

    cvt_f2b<<<dim3((nH  + 255) / 256), blk, 0, stream>>>(H,  Hb,   nH);
    cvt_f2b<<<dim3((nWq + 255) / 256), blk, 0, stream>>>(Wq, Wbuf, nWq);
    gemm_bt<true><<<dim3(HID / 64, S / 64), blk, 0, stream>>>(Hb, Wbuf, Qf, S, HID, HID);
    cvt_f2b<<<dim3((nWk + 255) / 256), blk, 0, stream>>>(Wk, Wbuf, nWk);
    gemm_bt<true><<<dim3(KVD / 64, S / 64), blk, 0, stream>>>(Hb, Wbuf, Kf, S, KVD, HID);
    cvt_f2b<<<dim3((nWk + 255) / 256), blk, 0, stream>>>(Wv, Wbuf, nWk);
    gemm_bt<true><<<dim3(KVD / 64, S / 64), blk, 0, stream>>>(Hb, Wbuf, Vf, S, KVD, HID);
    attn_stream<<<dim3(NH * (S / QT)), blk, 0, stream>>>(Qf, Kf, Vf, Ab, n_init_p, n_local_p);
    cvt_f2b<<<dim3((nWq + 255) / 256), blk, 0, stream>>>(Wo, Wbuf, nWq);
    gemm_bt<true><<<dim3(HID / 64, S / 64), blk, 0, stream>>>(Ab, Wbuf, (float*)d_out, S, HID, HID);
}

// Round 3
// 788.904 us; speedup vs baseline: 5.5796x; 5.5796x over previous
//
#include <hip/hip_runtime.h>
#include <hip/hip_bf16.h>

// Problem constants (fixed by the reference)
#define S     2048
#define HID   4096
#define NH    32
#define NKV   8
#define DH    128
#define KVD   1024   // NKV*DH

typedef unsigned short ushort_t;
typedef __attribute__((ext_vector_type(8))) __bf16 bf16x8;
typedef __attribute__((ext_vector_type(8))) unsigned short u16x8;
typedef __attribute__((ext_vector_type(4))) float f32x4;

static __device__ __forceinline__ unsigned short f2b(float f) {
    union { float f; unsigned int i; } x; x.f = f;
    unsigned int r = (x.i + 0x7fffu + ((x.i >> 16) & 1u)) >> 16;
    return (unsigned short)r;
}

// fp32 -> bf16 conversion, 4 elems/thread.
__global__ __launch_bounds__(256)
void cvt_f2b(const float* __restrict__ src, ushort_t* __restrict__ dst, int n4) {
    int i = blockIdx.x * 256 + threadIdx.x;
    if (i < n4) {
        float4 v = ((const float4*)src)[i];
        ushort4 o;
        o.x = f2b(v.x); o.y = f2b(v.y); o.z = f2b(v.z); o.w = f2b(v.w);
        ((ushort4*)dst)[i] = o;
    }
}

// C[M,N] = A[M,K] @ B[N,K]^T. bf16 inputs, fp32 accum.
// OMODE: 0 = fp32 C[M,N]; 1 = bf16 C[M,N]; 2 = bf16 transposed C^T[N,M].
// 64x64 tile, BK=32, 4 waves; verified fragment maps (m89/m91).
template <int OMODE>
__global__ __launch_bounds__(256)
void gemm_bt(const ushort_t* __restrict__ A, const ushort_t* __restrict__ B,
             void* __restrict__ Cv, int M, int N, int K) {
    __shared__ ushort_t As[64][40];   // 80 B rows: 2-way bank alias (free)
    __shared__ ushort_t Bs[64][40];

    const int tid   = threadIdx.x;
    const int w     = tid >> 6;
    const int lane  = tid & 63;
    const int mlane = lane & 15;
    const int q     = lane >> 4;
    const int m0    = blockIdx.y * 64;
    const int n0    = blockIdx.x * 64;
    const int lrow  = tid >> 2;
    const int lcol  = (tid & 3) * 8;

    f32x4 acc[4];
#pragma unroll
    for (int i = 0; i < 4; i++) acc[i] = (f32x4)(0.0f);

    const ushort_t* aptr = A + (long)(m0 + lrow) * K + lcol;
    const ushort_t* bptr = B + (long)(n0 + lrow) * K + lcol;

    for (int k0 = 0; k0 < K; k0 += 32) {
        u16x8 av = *(const u16x8*)(aptr + k0);
        u16x8 bv = *(const u16x8*)(bptr + k0);
        __syncthreads();
        *(u16x8*)&As[lrow][lcol] = av;
        *(u16x8*)&Bs[lrow][lcol] = bv;
        __syncthreads();
        bf16x8 af = *(const bf16x8*)&As[w * 16 + mlane][q * 8];
#pragma unroll
        for (int nt = 0; nt < 4; nt++) {
            bf16x8 bfr = *(const bf16x8*)&Bs[nt * 16 + mlane][q * 8];
            acc[nt] = __builtin_amdgcn_mfma_f32_16x16x32_bf16(af, bfr, acc[nt], 0, 0, 0);
        }
    }

#pragma unroll
    for (int nt = 0; nt < 4; nt++) {
        if (OMODE == 2) {
            int col  = n0 + nt * 16 + mlane;
            int row0 = m0 + w * 16 + q * 4;
            ushort4 o;
            o.x = f2b(acc[nt][0]); o.y = f2b(acc[nt][1]);
            o.z = f2b(acc[nt][2]); o.w = f2b(acc[nt][3]);
            *(ushort4*)((ushort_t*)Cv + (long)col * M + row0) = o;
        } else {
#pragma unroll
            for (int r = 0; r < 4; r++) {
                int row = m0 + w * 16 + q * 4 + r;
                int col = n0 + nt * 16 + mlane;
                if (OMODE == 0) ((float*)Cv)[(long)row * N + col] = acc[nt][r];
                else            ((ushort_t*)Cv)[(long)row * N + col] = f2b(acc[nt][r]);
            }
        }
    }
}

// MFMA flash attention with StreamingLLM mask.
// One block per (head, 64-query tile); wave w owns q-rows [i0+w*16, i0+w*16+16).
// Iterates 32-key tiles: sink tile 0 plus window tiles (disjoint coverage);
// general mask on boundary tiles. Online softmax in registers.
// Q,K bf16 [S][HID]/[S][KVD]; V transposed bf16 [KVD][S]; O bf16 [S][HID].
__global__ __launch_bounds__(256)
void attn_mfma(const ushort_t* __restrict__ Qb, const ushort_t* __restrict__ Kb,
               const ushort_t* __restrict__ Vt, ushort_t* __restrict__ O,
               const int* __restrict__ n_init_p, const int* __restrict__ n_local_p) {
    __shared__ ushort_t Ks[4][32][40];   // [k-step][key][dim-chunk] 80 B rows
    __shared__ ushort_t Vs[128][40];     // [dim][key]
    __shared__ ushort_t Ps[4][16][40];   // per-wave P tile (wave-private)

    const int n_init = *n_init_p, n_local = *n_local_p;
    const int tid   = threadIdx.x;
    const int w     = tid >> 6;
    const int lane  = tid & 63;
    const int mlane = lane & 15;
    const int q4    = lane >> 4;
    const int h     = blockIdx.x >> 5;     // 32 q-tiles per head
    const int qt    = blockIdx.x & 31;
    const int kh    = h >> 2;              // GQA: 4 q-heads per kv-head
    const int i0    = qt * 64;
    const int iMax  = i0 + 63;
    const int qrow_base = i0 + w * 16;

    // Q fragments (loop-invariant): A[m=mlane][k=ks*32+q4*8+j]
    bf16x8 qf[4];
    {
        const ushort_t* qp = Qb + (long)(qrow_base + mlane) * HID + h * DH + q4 * 8;
#pragma unroll
        for (int ks = 0; ks < 4; ks++) qf[ks] = *(const bf16x8*)(qp + ks * 32);
    }

    f32x4 oacc[8];
#pragma unroll
    for (int i = 0; i < 8; i++) oacc[i] = (f32x4)(0.0f);
    float mrow[4], lrow[4];
#pragma unroll
    for (int r = 0; r < 4; r++) { mrow[r] = -1e30f; lrow[r] = 0.0f; }

    int wstart = i0 - n_local + 1; if (wstart < 0) wstart = 0;
    const int tw   = (wstart <= n_init) ? 0 : (wstart >> 5);  // first window tile
    const int tmax = iMax >> 5;
    const float scale = 0.08838834764831845f;  // 1/sqrt(128)

    const int skk = tid >> 4, sc = tid & 15;   // K staging: key, dim-chunk
    const int vd  = tid >> 2, vc = tid & 3;    // V staging: dim, key-chunk
    ushort_t* psw = &Ps[w][0][0];

    for (int t = 0; t <= tmax; t++) {
        if (t > 0 && t < tw) continue;  // gap between sink and window (block-uniform)
        const int j0 = t * 32;

        u16x8 ka = *(const u16x8*)(Kb + (long)(j0 + skk) * KVD + kh * DH + sc * 8);
        u16x8 kc = *(const u16x8*)(Kb + (long)(j0 + skk + 16) * KVD + kh * DH + sc * 8);
        u16x8 va = *(const u16x8*)(Vt + (long)(kh * DH + vd) * S + j0 + vc * 8);
        u16x8 vb = *(const u16x8*)(Vt + (long)(kh * DH + vd + 64) * S + j0 + vc * 8);
        __syncthreads();  // prior iter's LDS reads done
        *(u16x8*)&Ks[sc >> 2][skk][(sc & 3) * 8] = ka;
        *(u16x8*)&Ks[sc >> 2][skk + 16][(sc & 3) * 8] = kc;
        *(u16x8*)&Vs[vd][vc * 8] = va;
        *(u16x8*)&Vs[vd + 64][vc * 8] = vb;
        __syncthreads();

        // QK^T: scores C-layout col=key(lane&15), row=q(q4*4+r)
        f32x4 sacc0 = (f32x4)(0.0f), sacc1 = (f32x4)(0.0f);
#pragma unroll
        for (int ks = 0; ks < 4; ks++) {
            bf16x8 k0f = *(const bf16x8*)&Ks[ks][mlane][q4 * 8];
            bf16x8 k1f = *(const bf16x8*)&Ks[ks][16 + mlane][q4 * 8];
            sacc0 = __builtin_amdgcn_mfma_f32_16x16x32_bf16(qf[ks], k0f, sacc0, 0, 0, 0);
            sacc1 = __builtin_amdgcn_mfma_f32_16x16x32_bf16(qf[ks], k1f, sacc1, 0, 0, 0);
        }

        const bool interior = (j0 + 31 <= i0) && (iMax - j0 < n_local);

#pragma unroll
        for (int r = 0; r < 4; r++) {
            float s0 = sacc0[r] * scale;
            float s1 = sacc1[r] * scale;
            if (!interior) {
                int qi = qrow_base + q4 * 4 + r;
                int jA = j0 + mlane, jB = jA + 16;
                bool okA = (jA <= qi) && ((jA < n_init) || (qi - jA < n_local));
                bool okB = (jB <= qi) && ((jB < n_init) || (qi - jB < n_local));
                s0 = okA ? s0 : -1e30f;
                s1 = okB ? s1 : -1e30f;
            }
            float a = fmaxf(s0, s1);
#pragma unroll
            for (int off = 1; off < 16; off <<= 1) a = fmaxf(a, __shfl_xor(a, off));
            float mnew  = fmaxf(mrow[r], a);
            float alpha = __expf(mrow[r] - mnew);
            float p0 = __expf(s0 - mnew), p1 = __expf(s1 - mnew);
            float ps = p0 + p1;
#pragma unroll
            for (int off = 1; off < 16; off <<= 1) ps += __shfl_xor(ps, off);
            lrow[r] = lrow[r] * alpha + ps;
            mrow[r] = mnew;
#pragma unroll
            for (int dt = 0; dt < 8; dt++) oacc[dt][r] *= alpha;
            psw[(q4 * 4 + r) * 40 + mlane]      = f2b(p0);
            psw[(q4 * 4 + r) * 40 + 16 + mlane] = f2b(p1);
        }

        // P (A-layout) from wave-private LDS; PV: B[n=d][k=j] = Vs[d][j]
        bf16x8 pf = *(const bf16x8*)&psw[mlane * 40 + q4 * 8];
#pragma unroll
        for (int dt = 0; dt < 8; dt++) {
            bf16x8 vf = *(const bf16x8*)&Vs[dt * 16 + mlane][q4 * 8];
            oacc[dt] = __builtin_amdgcn_mfma_f32_16x16x32_bf16(pf, vf, oacc[dt], 0, 0, 0);
        }
    }

    // Epilogue: O[q][h*DH + dt*16 + mlane] = oacc/l
#pragma unroll
    for (int r = 0; r < 4; r++) {
        float inv = 1.0f / lrow[r];
        int qrow = qrow_base + q4 * 4 + r;
        ushort_t* op = O + (long)qrow * HID + h * DH + mlane;
#pragma unroll
        for (int dt = 0; dt < 8; dt++)
            op[dt * 16] = f2b(oacc[dt][r] * inv);
    }
}

extern "C" void kernel_launch(void* const* d_in, const int* in_sizes, int n_in,
                              void* d_out, int out_size, void* d_ws, size_t ws_size,
                              hipStream_t stream) {
    const float* H  = (const float*)d_in[0];
    const float* Wq = (const float*)d_in[1];
    const float* Wk = (const float*)d_in[2];
    const float* Wv = (const float*)d_in[3];
    const float* Wo = (const float*)d_in[4];
    const int* n_init_p  = (const int*)d_in[5];
    const int* n_local_p = (const int*)d_in[6];

    // Workspace (bf16): Hb 16.8MB | Wbuf 33.6MB | Qb 16.8MB | Kb 4.2MB | Vt 4.2MB
    char* p = (char*)d_ws;
    ushort_t* Hb   = (ushort_t*)p;  p += (size_t)S * HID * 2;
    ushort_t* Wbuf = (ushort_t*)p;  p += (size_t)HID * HID * 2;
    ushort_t* Qb   = (ushort_t*)p;  p += (size_t)S * HID * 2;
    ushort_t* Kb   = (ushort_t*)p;  p += (size_t)S * KVD * 2;
    ushort_t* Vt   = (ushort_t*)p;
    ushort_t* Ab   = Hb;  // Hb dead after V-proj GEMM

    dim3 blk(256);
    const int nH = S * HID / 4, nWq = HID * HID / 4, nWk = KVD * HID / 4;

    cvt_f2b<<<dim3((nH  + 255) / 256), blk, 0, stream>>>(H,  Hb,   nH);
    cvt_f2b<<<dim3((nWq + 255) / 256), blk, 0, stream>>>(Wq, Wbuf, nWq);
    gemm_bt<1><<<dim3(HID / 64, S / 64), blk, 0, stream>>>(Hb, Wbuf, Qb, S, HID, HID);
    cvt_f2b<<<dim3((nWk + 255) / 256), blk, 0, stream>>>(Wk, Wbuf, nWk);
    gemm_bt<1><<<dim3(KVD / 64, S / 64), blk, 0, stream>>>(Hb, Wbuf, Kb, S, KVD, HID);
    cvt_f2b<<<dim3((nWk + 255) / 256), blk, 0, stream>>>(Wv, Wbuf, nWk);
    gemm_bt<2><<<dim3(KVD / 64, S / 64), blk, 0, stream>>>(Hb, Wbuf, Vt, S, KVD, HID);
    attn_mfma<<<dim3(NH * (S / 64)), blk, 0, stream>>>(Qb, Kb, Vt, Ab, n_init_p, n_local_p);
    cvt_f2b<<<dim3((nWq + 255) / 256), blk, 0, stream>>>(Wo, Wbuf, nWq);
    gemm_bt<0><<<dim3(HID / 64, S / 64), blk, 0, stream>>>(Ab, Wbuf, (float*)d_out, S, HID, HID);
}

// Round 4
// 585.672 us; speedup vs baseline: 7.5157x; 1.3470x over previous
//
#include <hip/hip_runtime.h>
#include <hip/hip_bf16.h>

// Problem constants (fixed by the reference)
#define S     2048
#define HID   4096
#define NH    32
#define NKV   8
#define DH    128
#define KVD   1024   // NKV*DH
#define NQK   6144   // HID + 2*KVD (fused QKV output width)
#define KDIM  4096   // projection K-dim

typedef unsigned short ushort_t;
typedef __attribute__((ext_vector_type(8))) __bf16 bf16x8;
typedef __attribute__((ext_vector_type(8))) unsigned short u16x8;
typedef __attribute__((ext_vector_type(4))) float f32x4;

static __device__ __forceinline__ unsigned short f2b(float f) {
    union { float f; unsigned int i; } x; x.f = f;
    unsigned int r = (x.i + 0x7fffu + ((x.i >> 16) & 1u)) >> 16;
    return (unsigned short)r;
}

// async global->LDS, 16B per lane; LDS dest = wave-uniform base + lane*16 (m97/m104).
static __device__ __forceinline__ void gload16(const void* g, void* l) {
    __builtin_amdgcn_global_load_lds(
        (const __attribute__((address_space(1))) void*)g,
        (__attribute__((address_space(3))) void*)l, 16, 0, 0);
}

// XOR chunk swizzle: tile stored as 512 chunks of 8 bf16; chunk(row,kc) kills
// the power-of-2 bank stride on fragment reads (2-way alias only -> free, m136).
static __device__ __forceinline__ int swz(int row, int kc) {
    return row * 4 + (kc ^ ((row >> 1) & 3));
}

// fp32 -> bf16 conversion, 4 elems/thread.
__global__ __launch_bounds__(256)
void cvt_f2b(const float* __restrict__ src, ushort_t* __restrict__ dst, int n4) {
    int i = blockIdx.x * 256 + threadIdx.x;
    if (i < n4) {
        float4 v = ((const float4*)src)[i];
        ushort4 o;
        o.x = f2b(v.x); o.y = f2b(v.y); o.z = f2b(v.z); o.w = f2b(v.w);
        ((ushort4*)dst)[i] = o;
    }
}

// m97-structure GEMM: C[M,N] = A[M,K] @ B[N,K]^T, bf16 in, fp32 accum.
// 128x128 tile, BK=32, 256 thr = 4 waves in 2x2; wave owns 64x64 (4x4 MFMA tiles).
// Staging: 4x global_load_lds dwordx4 per thread per K-step into swizzled LDS.
// MODE 0: fp32 C[M,N]. MODE 1: fused QKV epilogue (Q,K row-major bf16; V transposed).
template <int MODE>
__global__ __launch_bounds__(256)
void gemm128(const ushort_t* __restrict__ A, const ushort_t* __restrict__ B,
             float* __restrict__ Cf, ushort_t* __restrict__ Qb,
             ushort_t* __restrict__ Kb, ushort_t* __restrict__ Vt,
             int M, int N, int K) {
    __shared__ ushort_t As[128 * 32];   // 8 KB, chunk-swizzled
    __shared__ ushort_t Bs[128 * 32];

    const int tid   = threadIdx.x;
    const int w     = tid >> 6;
    const int lane  = tid & 63;
    const int mlane = lane & 15;
    const int q4    = lane >> 4;
    const int wr    = w >> 1, wc = w & 1;
    const int m0    = blockIdx.y * 128;
    const int n0    = blockIdx.x * 128;

    // Staging assignment: issue0 covers chunk c=tid, issue1 c=256+tid.
    const int r0 = tid >> 2,        k0c = (tid & 3) ^ ((r0 >> 1) & 3);
    const int r1 = 64 + (tid >> 2), k1c = (tid & 3) ^ ((r1 >> 1) & 3);
    const ushort_t* ap0 = A + (size_t)(m0 + r0) * K + k0c * 8;
    const ushort_t* ap1 = A + (size_t)(m0 + r1) * K + k1c * 8;
    const ushort_t* bp0 = B + (size_t)(n0 + r0) * K + k0c * 8;
    const ushort_t* bp1 = B + (size_t)(n0 + r1) * K + k1c * 8;
    ushort_t* lA0 = &As[(w * 64) * 8];        // wave-uniform LDS bases
    ushort_t* lA1 = &As[(256 + w * 64) * 8];
    ushort_t* lB0 = &Bs[(w * 64) * 8];
    ushort_t* lB1 = &Bs[(256 + w * 64) * 8];

    // Fragment LDS addresses (loop-invariant)
    const ushort_t* afp[4];
    const ushort_t* bfp[4];
#pragma unroll
    for (int mt = 0; mt < 4; mt++) {
        int row = wr * 64 + mt * 16 + mlane;
        afp[mt] = &As[swz(row, q4) * 8];
    }
#pragma unroll
    for (int nt = 0; nt < 4; nt++) {
        int col = wc * 64 + nt * 16 + mlane;
        bfp[nt] = &Bs[swz(col, q4) * 8];
    }

    f32x4 acc[4][4];
#pragma unroll
    for (int i = 0; i < 4; i++)
#pragma unroll
        for (int j = 0; j < 4; j++) acc[i][j] = (f32x4)(0.0f);

    for (int k0 = 0; k0 < K; k0 += 32) {
        __syncthreads();                  // prior iter's LDS reads done
        gload16(ap0 + k0, lA0);
        gload16(ap1 + k0, lA1);
        gload16(bp0 + k0, lB0);
        gload16(bp1 + k0, lB1);
        __syncthreads();                  // compiler drains vmcnt before barrier

        bf16x8 af[4], bf[4];
#pragma unroll
        for (int mt = 0; mt < 4; mt++) af[mt] = *(const bf16x8*)afp[mt];
#pragma unroll
        for (int nt = 0; nt < 4; nt++) bf[nt] = *(const bf16x8*)bfp[nt];
#pragma unroll
        for (int mt = 0; mt < 4; mt++)
#pragma unroll
            for (int nt = 0; nt < 4; nt++)
                acc[mt][nt] = __builtin_amdgcn_mfma_f32_16x16x32_bf16(
                    af[mt], bf[nt], acc[mt][nt], 0, 0, 0);
    }

    // Epilogue. C/D map: col = n-tile + mlane, row = m-tile + q4*4 + r.
#pragma unroll
    for (int mt = 0; mt < 4; mt++) {
#pragma unroll
        for (int nt = 0; nt < 4; nt++) {
            int row = m0 + wr * 64 + mt * 16 + q4 * 4;
            int col = n0 + wc * 64 + nt * 16 + mlane;
            if (MODE == 0) {
#pragma unroll
                for (int r = 0; r < 4; r++)
                    Cf[(size_t)(row + r) * N + col] = acc[mt][nt][r];
            } else {
                if (n0 < HID) {               // Q region (block-uniform)
#pragma unroll
                    for (int r = 0; r < 4; r++)
                        Qb[(size_t)(row + r) * HID + col] = f2b(acc[mt][nt][r]);
                } else if (n0 < HID + KVD) {  // K region
                    int c2 = col - HID;
#pragma unroll
                    for (int r = 0; r < 4; r++)
                        Kb[(size_t)(row + r) * KVD + c2] = f2b(acc[mt][nt][r]);
                } else {                      // V region: write transposed [KVD][S]
                    int c2 = col - (HID + KVD);
                    ushort4 o;
                    o.x = f2b(acc[mt][nt][0]); o.y = f2b(acc[mt][nt][1]);
                    o.z = f2b(acc[mt][nt][2]); o.w = f2b(acc[mt][nt][3]);
                    *(ushort4*)(Vt + (size_t)c2 * S + row) = o;
                }
            }
        }
    }
}

// MFMA flash attention with StreamingLLM mask (unchanged from round 3).
__global__ __launch_bounds__(256)
void attn_mfma(const ushort_t* __restrict__ Qb, const ushort_t* __restrict__ Kb,
               const ushort_t* __restrict__ Vt, ushort_t* __restrict__ O,
               const int* __restrict__ n_init_p, const int* __restrict__ n_local_p) {
    __shared__ ushort_t Ks[4][32][40];
    __shared__ ushort_t Vs[128][40];
    __shared__ ushort_t Ps[4][16][40];

    const int n_init = *n_init_p, n_local = *n_local_p;
    const int tid   = threadIdx.x;
    const int w     = tid >> 6;
    const int lane  = tid & 63;
    const int mlane = lane & 15;
    const int q4    = lane >> 4;
    const int h     = blockIdx.x >> 5;
    const int qt    = blockIdx.x & 31;
    const int kh    = h >> 2;
    const int i0    = qt * 64;
    const int iMax  = i0 + 63;
    const int qrow_base = i0 + w * 16;

    bf16x8 qf[4];
    {
        const ushort_t* qp = Qb + (size_t)(qrow_base + mlane) * HID + h * DH + q4 * 8;
#pragma unroll
        for (int ks = 0; ks < 4; ks++) qf[ks] = *(const bf16x8*)(qp + ks * 32);
    }

    f32x4 oacc[8];
#pragma unroll
    for (int i = 0; i < 8; i++) oacc[i] = (f32x4)(0.0f);
    float mrow[4], lrow[4];
#pragma unroll
    for (int r = 0; r < 4; r++) { mrow[r] = -1e30f; lrow[r] = 0.0f; }

    int wstart = i0 - n_local + 1; if (wstart < 0) wstart = 0;
    const int tw   = (wstart <= n_init) ? 0 : (wstart >> 5);
    const int tmax = iMax >> 5;
    const float scale = 0.08838834764831845f;

    const int skk = tid >> 4, sc = tid & 15;
    const int vd  = tid >> 2, vc = tid & 3;
    ushort_t* psw = &Ps[w][0][0];

    for (int t = 0; t <= tmax; t++) {
        if (t > 0 && t < tw) continue;
        const int j0 = t * 32;

        u16x8 ka = *(const u16x8*)(Kb + (size_t)(j0 + skk) * KVD + kh * DH + sc * 8);
        u16x8 kc = *(const u16x8*)(Kb + (size_t)(j0 + skk + 16) * KVD + kh * DH + sc * 8);
        u16x8 va = *(const u16x8*)(Vt + (size_t)(kh * DH + vd) * S + j0 + vc * 8);
        u16x8 vb = *(const u16x8*)(Vt + (size_t)(kh * DH + vd + 64) * S + j0 + vc * 8);
        __syncthreads();
        *(u16x8*)&Ks[sc >> 2][skk][(sc & 3) * 8] = ka;
        *(u16x8*)&Ks[sc >> 2][skk + 16][(sc & 3) * 8] = kc;
        *(u16x8*)&Vs[vd][vc * 8] = va;
        *(u16x8*)&Vs[vd + 64][vc * 8] = vb;
        __syncthreads();

        f32x4 sacc0 = (f32x4)(0.0f), sacc1 = (f32x4)(0.0f);
#pragma unroll
        for (int ks = 0; ks < 4; ks++) {
            bf16x8 k0f = *(const bf16x8*)&Ks[ks][mlane][q4 * 8];
            bf16x8 k1f = *(const bf16x8*)&Ks[ks][16 + mlane][q4 * 8];
            sacc0 = __builtin_amdgcn_mfma_f32_16x16x32_bf16(qf[ks], k0f, sacc0, 0, 0, 0);
            sacc1 = __builtin_amdgcn_mfma_f32_16x16x32_bf16(qf[ks], k1f, sacc1, 0, 0, 0);
        }

        const bool interior = (j0 + 31 <= i0) && (iMax - j0 < n_local);

#pragma unroll
        for (int r = 0; r < 4; r++) {
            float s0 = sacc0[r] * scale;
            float s1 = sacc1[r] * scale;
            if (!interior) {
                int qi = qrow_base + q4 * 4 + r;
                int jA = j0 + mlane, jB = jA + 16;
                bool okA = (jA <= qi) && ((jA < n_init) || (qi - jA < n_local));
                bool okB = (jB <= qi) && ((jB < n_init) || (qi - jB < n_local));
                s0 = okA ? s0 : -1e30f;
                s1 = okB ? s1 : -1e30f;
            }
            float a = fmaxf(s0, s1);
#pragma unroll
            for (int off = 1; off < 16; off <<= 1) a = fmaxf(a, __shfl_xor(a, off));
            float mnew  = fmaxf(mrow[r], a);
            float alpha = __expf(mrow[r] - mnew);
            float p0 = __expf(s0 - mnew), p1 = __expf(s1 - mnew);
            float ps = p0 + p1;
#pragma unroll
            for (int off = 1; off < 16; off <<= 1) ps += __shfl_xor(ps, off);
            lrow[r] = lrow[r] * alpha + ps;
            mrow[r] = mnew;
#pragma unroll
            for (int dt = 0; dt < 8; dt++) oacc[dt][r] *= alpha;
            psw[(q4 * 4 + r) * 40 + mlane]      = f2b(p0);
            psw[(q4 * 4 + r) * 40 + 16 + mlane] = f2b(p1);
        }

        bf16x8 pf = *(const bf16x8*)&psw[mlane * 40 + q4 * 8];
#pragma unroll
        for (int dt = 0; dt < 8; dt++) {
            bf16x8 vf = *(const bf16x8*)&Vs[dt * 16 + mlane][q4 * 8];
            oacc[dt] = __builtin_amdgcn_mfma_f32_16x16x32_bf16(pf, vf, oacc[dt], 0, 0, 0);
        }
    }

#pragma unroll
    for (int r = 0; r < 4; r++) {
        float inv = 1.0f / lrow[r];
        int qrow = qrow_base + q4 * 4 + r;
        ushort_t* op = O + (size_t)qrow * HID + h * DH + mlane;
#pragma unroll
        for (int dt = 0; dt < 8; dt++)
            op[dt * 16] = f2b(oacc[dt][r] * inv);
    }
}

extern "C" void kernel_launch(void* const* d_in, const int* in_sizes, int n_in,
                              void* d_out, int out_size, void* d_ws, size_t ws_size,
                              hipStream_t stream) {
    const float* H  = (const float*)d_in[0];
    const float* Wq = (const float*)d_in[1];
    const float* Wk = (const float*)d_in[2];
    const float* Wv = (const float*)d_in[3];
    const float* Wo = (const float*)d_in[4];
    const int* n_init_p  = (const int*)d_in[5];
    const int* n_local_p = (const int*)d_in[6];

    // Workspace: Hb 16.8 | Wbuf 50.3 (QKV concat; reused for Wo) | Qb 16.8 |
    //            Kb 4.2 | Vt 4.2  => ~92.3 MB
    char* p = (char*)d_ws;
    ushort_t* Hb   = (ushort_t*)p;  p += (size_t)S * HID * 2;
    ushort_t* Wbuf = (ushort_t*)p;  p += (size_t)NQK * KDIM * 2;
    ushort_t* Qb   = (ushort_t*)p;  p += (size_t)S * HID * 2;
    ushort_t* Kb   = (ushort_t*)p;  p += (size_t)S * KVD * 2;
    ushort_t* Vt   = (ushort_t*)p;
    ushort_t* Ab   = Hb;  // Hb dead after QKV GEMM

    dim3 blk(256);
    const int nH = S * HID / 4, nWq = HID * KDIM / 4, nWk = KVD * KDIM / 4;

    cvt_f2b<<<dim3((nH  + 255) / 256), blk, 0, stream>>>(H,  Hb, nH);
    cvt_f2b<<<dim3((nWq + 255) / 256), blk, 0, stream>>>(Wq, Wbuf, nWq);
    cvt_f2b<<<dim3((nWk + 255) / 256), blk, 0, stream>>>(Wk, Wbuf + (size_t)HID * KDIM, nWk);
    cvt_f2b<<<dim3((nWk + 255) / 256), blk, 0, stream>>>(Wv, Wbuf + (size_t)(HID + KVD) * KDIM, nWk);
    gemm128<1><<<dim3(NQK / 128, S / 128), blk, 0, stream>>>(
        Hb, Wbuf, nullptr, Qb, Kb, Vt, S, NQK, KDIM);
    attn_mfma<<<dim3(NH * (S / 64)), blk, 0, stream>>>(Qb, Kb, Vt, Ab, n_init_p, n_local_p);
    cvt_f2b<<<dim3((nWq + 255) / 256), blk, 0, stream>>>(Wo, Wbuf, nWq);
    gemm128<0><<<dim3(HID / 128, S / 128), blk, 0, stream>>>(
        Ab, Wbuf, (float*)d_out, nullptr, nullptr, nullptr, S, HID, KDIM);
}